// Round 4
// baseline (145.308 us; speedup 1.0000x reference)
//
#include <hip/hip_runtime.h>

#define DEVINL __device__ __forceinline__

constexpr int E    = 768;
constexpr int TSEQ = 512;
constexpr int NH   = 12;
constexpr int HD   = 64;
constexpr float RSCALE = 0.036084391824351615f; // 1/sqrt(768)

typedef short bf16x8 __attribute__((ext_vector_type(8)));
typedef float floatx4 __attribute__((ext_vector_type(4)));

DEVINL short f2bf(float x) {
    union { float f; unsigned u; } v; v.f = x;
    unsigned r = v.u + 0x7FFFu + ((v.u >> 16) & 1u);
    return (short)(r >> 16);
}
DEVINL float bf2f(short s) {
    union { unsigned u; float f; } v;
    v.u = ((unsigned)(unsigned short)s) << 16;
    return v.f;
}

DEVINL bf16x8 cvt8(const float* p) {
    float4 f0 = *(const float4*)p;
    float4 f1 = *(const float4*)(p + 4);
    bf16x8 o;
    o[0] = f2bf(f0.x); o[1] = f2bf(f0.y); o[2] = f2bf(f0.z); o[3] = f2bf(f0.w);
    o[4] = f2bf(f1.x); o[5] = f2bf(f1.y); o[6] = f2bf(f1.z); o[7] = f2bf(f1.w);
    return o;
}

// ---------------------------------------------------------------------------
// Kernel 1: QKV projections via MFMA, fp32 inputs converted in-register.
// y = x @ W^T + b (fp32 in -> bf16 staged -> fp32 accum -> bf16 out).
// Block = 64x64 output tile (one head wide), 4 waves.
// Software-pipelined: next K-chunk's global loads issue before the MFMA phase.
// ---------------------------------------------------------------------------
__global__ __launch_bounds__(256) void qkv_mfma(
    const float* __restrict__ x,
    const float* __restrict__ wq, const float* __restrict__ bq,
    const float* __restrict__ wk, const float* __restrict__ bk,
    const float* __restrict__ wv, const float* __restrict__ bv,
    short* __restrict__ Qo, short* __restrict__ Ko, short* __restrict__ Vo)
{
    const float* W; const float* bias; short* outp;
    if (blockIdx.z == 0)      { W = wq; bias = bq; outp = Qo; }
    else if (blockIdx.z == 1) { W = wk; bias = bk; outp = Ko; }
    else                      { W = wv; bias = bv; outp = Vo; }

    __shared__ short As[64 * 72];
    __shared__ short Bs[64 * 72];

    const int m0   = blockIdx.x * 64;
    const int n0   = blockIdx.y * 64;    // == head * 64
    const int tid  = threadIdx.x;
    const int wvi  = tid >> 6;
    const int lane = tid & 63;
    const int col  = lane & 15;
    const int quad = lane >> 4;

    const int r0 = tid >> 3,   kc0 = tid & 7;
    const int r1 = r0 + 32;

    floatx4 acc[4];
    #pragma unroll
    for (int i = 0; i < 4; i++) acc[i] = (floatx4){0.f, 0.f, 0.f, 0.f};

    // prefetch k0 = 0
    bf16x8 a0 = cvt8(&x[(size_t)(m0 + r0) * E + kc0 * 8]);
    bf16x8 a1 = cvt8(&x[(size_t)(m0 + r1) * E + kc0 * 8]);
    bf16x8 b0 = cvt8(&W[(size_t)(n0 + r0) * E + kc0 * 8]);
    bf16x8 b1 = cvt8(&W[(size_t)(n0 + r1) * E + kc0 * 8]);

    for (int k0 = 0; k0 < E; k0 += 64) {
        __syncthreads();
        *(bf16x8*)&As[r0 * 72 + kc0 * 8] = a0;
        *(bf16x8*)&As[r1 * 72 + kc0 * 8] = a1;
        *(bf16x8*)&Bs[r0 * 72 + kc0 * 8] = b0;
        *(bf16x8*)&Bs[r1 * 72 + kc0 * 8] = b1;
        __syncthreads();

        if (k0 + 64 < E) {     // prefetch next chunk; latency hidden by MFMAs
            a0 = cvt8(&x[(size_t)(m0 + r0) * E + k0 + 64 + kc0 * 8]);
            a1 = cvt8(&x[(size_t)(m0 + r1) * E + k0 + 64 + kc0 * 8]);
            b0 = cvt8(&W[(size_t)(n0 + r0) * E + k0 + 64 + kc0 * 8]);
            b1 = cvt8(&W[(size_t)(n0 + r1) * E + k0 + 64 + kc0 * 8]);
        }

        #pragma unroll
        for (int k32 = 0; k32 < 2; k32++) {
            bf16x8 bf = *(const bf16x8*)&Bs[(wvi*16 + col) * 72 + k32*32 + quad*8];
            #pragma unroll
            for (int ms = 0; ms < 4; ms++) {
                bf16x8 af = *(const bf16x8*)&As[(ms*16 + col) * 72 + k32*32 + quad*8];
                acc[ms] = __builtin_amdgcn_mfma_f32_16x16x32_bf16(af, bf, acc[ms], 0, 0, 0);
            }
        }
    }

    const float bn = bias[n0 + wvi*16 + col];
    const int h = blockIdx.y;
    #pragma unroll
    for (int ms = 0; ms < 4; ms++) {
        #pragma unroll
        for (int r = 0; r < 4; r++) {
            int m = m0 + ms*16 + quad*4 + r;
            int bb = m >> 9, l = m & 511;
            outp[(((size_t)(bb*NH + h)) * TSEQ + l) * HD + wvi*16 + col] =
                f2bf(acc[ms][r] + bn);
        }
    }
}

// ---------------------------------------------------------------------------
// Kernel 2: Kp[b][h][o][t][d] = (1/scale) * sum_i w1[(h*8+o)*12+i] * K[b][i][t][d]
// ---------------------------------------------------------------------------
__global__ __launch_bounds__(256) void kmix_kernel(
    const short* __restrict__ K,   // [B,12,T,64] bf16
    const float* __restrict__ w1,  // [96,12] fp32
    short* __restrict__ Kp)        // [B,12,8,T,64] bf16
{
    const int g  = blockIdx.x * 256 + threadIdx.x;   // chunk of 8 bf16
    const int d8 = g & 7;
    const int t  = (g >> 3) & 511;
    const int o  = (g >> 12) & 7;
    const int bh = g >> 15;          // b*12 + h
    const int h  = bh % NH;
    const int b  = bh / NH;

    float acc[8] = {};
    #pragma unroll
    for (int i = 0; i < 12; i++) {
        float w = w1[(h*8 + o)*12 + i] * RSCALE;
        bf16x8 kv = *(const bf16x8*)&K[(((size_t)(b*NH + i) * TSEQ) + t) * HD + d8*8];
        #pragma unroll
        for (int j = 0; j < 8; j++)
            acc[j] = fmaf(w, bf2f(kv[j]), acc[j]);
    }
    bf16x8 outv;
    #pragma unroll
    for (int j = 0; j < 8; j++) outv[j] = f2bf(acc[j]);
    *(bf16x8*)&Kp[(size_t)g * 8] = outv;
}

// ---------------------------------------------------------------------------
// Per-position talking-heads MLP (conv1 weights folded into Kp; b1 here).
// ---------------------------------------------------------------------------
DEVINL float mlp_eval(const float s[8],
                      const float b1r[8], const float w2r[8], float b2r,
                      const float w3r[4], const float b3r[4],
                      const float w4r[4], float b4r)
{
    float z2 = b2r;
    #pragma unroll
    for (int o = 0; o < 8; o++) {
        float z1 = fmaxf(s[o] + b1r[o], 0.0f);
        z2 = fmaf(z1, w2r[o], z2);
    }
    float r = b4r;
    #pragma unroll
    for (int j = 0; j < 4; j++) {
        float z3 = fmaxf(fmaf(z2, w3r[j], b3r[j]), 0.0f);
        r = fmaf(z3, w4r[j], r);
    }
    return r;
}

// group-of-8 padded row offset (conflict-free transpose writes + aligned b128 reads)
DEVINL int vrow(int r) { return r*40 + (r >> 3)*8; }

// ---------------------------------------------------------------------------
// Kernel 3: MFMA attention. Block = (b, h, l-tile 64, t-quarter 128).
// Software-pipelined: tile it+1's global loads issue right after the LDS
// publish barrier, hidden behind the S'/MLP compute phase.
// ---------------------------------------------------------------------------
__global__ __launch_bounds__(256, 3) void attn_mfma(
    const short* __restrict__ Qg,   // [B,12,T,64] bf16
    const short* __restrict__ Kg,   // [B,12,8,T,64] bf16
    const short* __restrict__ Vg,   // [B,12,T,64] bf16
    const float* __restrict__ b1, const float* __restrict__ w2,
    const float* __restrict__ b2, const float* __restrict__ w3,
    const float* __restrict__ b3, const float* __restrict__ w4,
    const float* __restrict__ b4,
    float* __restrict__ Pout)       // [768][64][64] fp32 partials
{
    __shared__ short Ks[256 * 72];   // [o*32+t][72]  (64d used)
    __shared__ short Vt[2624];       // transposed V: [d][t], group-padded
    __shared__ short As[2624];       // A weights:    [l][t], group-padded

    const int blk = blockIdx.x;          // ((b*12+h)*8+lt)*4 + qtr
    const int qtr = blk & 3;
    const int lt  = (blk >> 2) & 7;
    const int bh  = blk >> 5;
    const int h   = bh % NH;
    const int l0  = lt * 64;
    const int tb  = qtr * 128;

    const int tid  = threadIdx.x;
    const int wv   = tid >> 6;
    const int lane = tid & 63;
    const int col  = lane & 15;
    const int quad = lane >> 4;
    const int wl   = wv >> 1;   // l-half for S'
    const int wt   = wv & 1;    // t-half for S'

    float b1r[8], w2r[8], w3r[4], b3r[4], w4r[4];
    #pragma unroll
    for (int o = 0; o < 8; o++) { b1r[o] = b1[h*8+o]; w2r[o] = w2[h*8+o]; }
    #pragma unroll
    for (int j = 0; j < 4; j++) { w3r[j] = w3[h*4+j]; b3r[j] = b3[h*4+j]; w4r[j] = w4[h*4+j]; }
    const float b2r = b2[h];
    const float b4r = b4[h];

    bf16x8 qa[2][2];
    {
        const short* qb = Qg + ((size_t)bh * TSEQ + l0 + wl*32 + col) * HD;
        qa[0][0] = *(const bf16x8*)&qb[quad*8];
        qa[0][1] = *(const bf16x8*)&qb[32 + quad*8];
        qa[1][0] = *(const bf16x8*)&qb[16*HD + quad*8];
        qa[1][1] = *(const bf16x8*)&qb[16*HD + 32 + quad*8];
    }

    floatx4 accO[4];
    #pragma unroll
    for (int d16 = 0; d16 < 4; d16++) accO[d16] = (floatx4){0.f, 0.f, 0.f, 0.f};

    const short* kbase = Kg + (size_t)bh * 8 * TSEQ * HD;
    const short* vbase = Vg + (size_t)bh * TSEQ * HD;

    const int tl = tid >> 3;   // 0..31 staging row
    const int dc = tid & 7;    // staging 16B chunk

    // prefetch tile 0
    bf16x8 ktmp[8]; bf16x8 vtmp;
    #pragma unroll
    for (int o = 0; o < 8; o++)
        ktmp[o] = *(const bf16x8*)&kbase[((size_t)o * TSEQ + tb + tl) * HD + dc*8];
    vtmp = *(const bf16x8*)&vbase[(size_t)(tb + tl) * HD + dc*8];

    for (int it = 0; it < 4; it++) {
        __syncthreads();   // all reads of previous tile's Ks/Vt/As done

        #pragma unroll
        for (int o = 0; o < 8; o++)
            *(bf16x8*)&Ks[(o*32 + tl)*72 + dc*8] = ktmp[o];
        #pragma unroll
        for (int j = 0; j < 8; j++)
            Vt[vrow(dc*8 + j) + tl] = vtmp[j];   // transpose: Vt[d][t]

        __syncthreads();

        if (it < 3) {      // prefetch next tile; hidden behind S'/MLP phase
            const int t1 = tb + (it + 1) * 32;
            #pragma unroll
            for (int o = 0; o < 8; o++)
                ktmp[o] = *(const bf16x8*)&kbase[((size_t)o * TSEQ + t1 + tl) * HD + dc*8];
            vtmp = *(const bf16x8*)&vbase[(size_t)(t1 + tl) * HD + dc*8];
        }

        floatx4 accS[8][2];
        #pragma unroll
        for (int o = 0; o < 8; o++) {
            accS[o][0] = (floatx4){0.f, 0.f, 0.f, 0.f};
            accS[o][1] = (floatx4){0.f, 0.f, 0.f, 0.f};
        }
        #pragma unroll
        for (int k32 = 0; k32 < 2; k32++) {
            #pragma unroll
            for (int o = 0; o < 8; o++) {
                bf16x8 bf = *(const bf16x8*)&Ks[(o*32 + wt*16 + col)*72 + k32*32 + quad*8];
                accS[o][0] = __builtin_amdgcn_mfma_f32_16x16x32_bf16(qa[0][k32], bf, accS[o][0], 0, 0, 0);
                accS[o][1] = __builtin_amdgcn_mfma_f32_16x16x32_bf16(qa[1][k32], bf, accS[o][1], 0, 0, 0);
            }
        }

        #pragma unroll
        for (int li = 0; li < 2; li++) {
            #pragma unroll
            for (int r = 0; r < 4; r++) {
                float s[8];
                #pragma unroll
                for (int o = 0; o < 8; o++) s[o] = accS[o][li][r];
                float a = mlp_eval(s, b1r, w2r, b2r, w3r, b3r, w4r, b4r);
                As[vrow(wl*32 + li*16 + quad*4 + r) + wt*16 + col] = f2bf(a);
            }
        }
        __syncthreads();

        bf16x8 af = *(const bf16x8*)&As[vrow(wv*16 + col) + quad*8];
        #pragma unroll
        for (int d16 = 0; d16 < 4; d16++) {
            bf16x8 vf = *(const bf16x8*)&Vt[vrow(d16*16 + col) + quad*8];
            accO[d16] = __builtin_amdgcn_mfma_f32_16x16x32_bf16(af, vf, accO[d16], 0, 0, 0);
        }
    }

    float* pb = Pout + (size_t)blk * 64 * 64;
    #pragma unroll
    for (int d16 = 0; d16 < 4; d16++)
        #pragma unroll
        for (int r = 0; r < 4; r++)
            pb[(wv*16 + quad*4 + r) * 64 + d16*16 + col] = accO[d16][r];
}

// ---------------------------------------------------------------------------
// Kernel 4: sum 4 t-quarter partials, scatter to out[b][l][h*64+d].
// ---------------------------------------------------------------------------
__global__ __launch_bounds__(256) void reduce_kernel(
    const float* __restrict__ P, float* __restrict__ out)
{
    const int gi  = blockIdx.x * 256 + threadIdx.x;  // float4 units, 196608 total
    const int d4  = gi & 15;
    const int r   = (gi >> 4) & 63;
    const int grp = gi >> 10;            // (b*12+h)*8 + lt
    const int lt  = grp & 7;
    const int bh  = grp >> 3;
    const int h   = bh % NH;
    const int b   = bh / NH;

    const float* p0 = P + (size_t)grp * 4 * 4096 + r * 64 + d4 * 4;
    float4 s0 = *(const float4*)&p0[0];
    float4 s1 = *(const float4*)&p0[4096];
    float4 s2 = *(const float4*)&p0[8192];
    float4 s3 = *(const float4*)&p0[12288];
    float4 s;
    s.x = (s0.x + s1.x) + (s2.x + s3.x);
    s.y = (s0.y + s1.y) + (s2.y + s3.y);
    s.z = (s0.z + s1.z) + (s2.z + s3.z);
    s.w = (s0.w + s1.w) + (s2.w + s3.w);
    *(float4*)&out[((size_t)(b*TSEQ + lt*64 + r)) * E + h*64 + d4*4] = s;
}

// ---------------------------------------------------------------------------
extern "C" void kernel_launch(void* const* d_in, const int* in_sizes, int n_in,
                              void* d_out, int out_size, void* d_ws, size_t ws_size,
                              hipStream_t stream) {
    const float* x  = (const float*)d_in[0];
    const float* wq = (const float*)d_in[1];
    const float* bq = (const float*)d_in[2];
    const float* wk = (const float*)d_in[3];
    const float* bk = (const float*)d_in[4];
    const float* wv = (const float*)d_in[5];
    const float* bv = (const float*)d_in[6];
    const float* w1 = (const float*)d_in[7];
    const float* b1 = (const float*)d_in[8];
    const float* w2 = (const float*)d_in[9];
    const float* b2 = (const float*)d_in[10];
    const float* w3 = (const float*)d_in[11];
    const float* b3 = (const float*)d_in[12];
    const float* w4 = (const float*)d_in[13];
    const float* b4 = (const float*)d_in[14];
    float* out = (float*)d_out;

    short* Qb = (short*)d_ws;                       // 786432 bf16
    short* Kb = Qb + 786432;                        // 786432 bf16
    short* Vb = Kb + 786432;                        // 786432 bf16
    short* Kp = Vb + 786432;                        // 6291456 bf16
    float* P  = (float*)(Kp + 6291456);             // 3145728 fp32

    qkv_mfma<<<dim3(16, 12, 3), 256, 0, stream>>>(x, wq, bq, wk, bk, wv, bv, Qb, Kb, Vb);
    kmix_kernel<<<3072, 256, 0, stream>>>(Kb, w1, Kp);
    attn_mfma<<<768, 256, 0, stream>>>(Qb, Kp, Vb, b1, w2, b2, w3, b3, w4, b4, P);
    reduce_kernel<<<768, 256, 0, stream>>>(P, out);
}

// Round 5
// 132.227 us; speedup vs baseline: 1.0989x; 1.0989x over previous
//
#include <hip/hip_runtime.h>

#define DEVINL __device__ __forceinline__

constexpr int E    = 768;
constexpr int TSEQ = 512;
constexpr int NH   = 12;
constexpr int HD   = 64;
constexpr float RSCALE = 0.036084391824351615f; // 1/sqrt(768)

typedef short bf16x8 __attribute__((ext_vector_type(8)));
typedef float floatx4 __attribute__((ext_vector_type(4)));

DEVINL short f2bf(float x) {
    union { float f; unsigned u; } v; v.f = x;
    unsigned r = v.u + 0x7FFFu + ((v.u >> 16) & 1u);
    return (short)(r >> 16);
}
DEVINL float bf2f(short s) {
    union { unsigned u; float f; } v;
    v.u = ((unsigned)(unsigned short)s) << 16;
    return v.f;
}

// ---------------------------------------------------------------------------
// Kernel 0: fp32 -> bf16 conversion for x, wq, wk, wv (one pass).
// ---------------------------------------------------------------------------
__global__ __launch_bounds__(256) void convert_kernel(
    const float* __restrict__ x,  const float* __restrict__ wq,
    const float* __restrict__ wk, const float* __restrict__ wv,
    short* __restrict__ xb, short* __restrict__ wqb,
    short* __restrict__ wkb, short* __restrict__ wvb)
{
    const int g = blockIdx.x * 256 + threadIdx.x;    // 319488 threads total
    const float* src; short* dst; int off;
    if (g < 98304)       { src = x;  dst = xb;  off = g * 8; }
    else if (g < 172032) { src = wq; dst = wqb; off = (g - 98304) * 8; }
    else if (g < 245760) { src = wk; dst = wkb; off = (g - 172032) * 8; }
    else                 { src = wv; dst = wvb; off = (g - 245760) * 8; }
    float4 f0 = *(const float4*)&src[off];
    float4 f1 = *(const float4*)&src[off + 4];
    bf16x8 o;
    o[0] = f2bf(f0.x); o[1] = f2bf(f0.y); o[2] = f2bf(f0.z); o[3] = f2bf(f0.w);
    o[4] = f2bf(f1.x); o[5] = f2bf(f1.y); o[6] = f2bf(f1.z); o[7] = f2bf(f1.w);
    *(bf16x8*)&dst[off] = o;
}

// ---------------------------------------------------------------------------
// Kernel 1: QKV projections via MFMA.  y = x @ W^T + b  (bf16 in, bf16 out,
// fp32 accum).  Block = 64x64 output tile (one head wide), 4 waves.
// ---------------------------------------------------------------------------
__global__ __launch_bounds__(256) void qkv_mfma(
    const short* __restrict__ xb,
    const short* __restrict__ wqb, const float* __restrict__ bq,
    const short* __restrict__ wkb, const float* __restrict__ bk,
    const short* __restrict__ wvb, const float* __restrict__ bv,
    short* __restrict__ Qo, short* __restrict__ Ko, short* __restrict__ Vo)
{
    const short* W; const float* bias; short* outp;
    if (blockIdx.z == 0)      { W = wqb; bias = bq; outp = Qo; }
    else if (blockIdx.z == 1) { W = wkb; bias = bk; outp = Ko; }
    else                      { W = wvb; bias = bv; outp = Vo; }

    __shared__ short As[64 * 72];
    __shared__ short Bs[64 * 72];

    const int m0   = blockIdx.x * 64;
    const int n0   = blockIdx.y * 64;    // == head * 64
    const int tid  = threadIdx.x;
    const int wvi  = tid >> 6;
    const int lane = tid & 63;
    const int col  = lane & 15;
    const int quad = lane >> 4;

    const int r0 = tid >> 3,   kc0 = tid & 7;
    const int r1 = r0 + 32;

    floatx4 acc[4];
    #pragma unroll
    for (int i = 0; i < 4; i++) acc[i] = (floatx4){0.f, 0.f, 0.f, 0.f};

    for (int k0 = 0; k0 < E; k0 += 64) {
        bf16x8 a0 = *(const bf16x8*)&xb[(size_t)(m0 + r0) * E + k0 + kc0 * 8];
        bf16x8 a1 = *(const bf16x8*)&xb[(size_t)(m0 + r1) * E + k0 + kc0 * 8];
        bf16x8 b0 = *(const bf16x8*)&W [(size_t)(n0 + r0) * E + k0 + kc0 * 8];
        bf16x8 b1 = *(const bf16x8*)&W [(size_t)(n0 + r1) * E + k0 + kc0 * 8];
        __syncthreads();
        *(bf16x8*)&As[r0 * 72 + kc0 * 8] = a0;
        *(bf16x8*)&As[r1 * 72 + kc0 * 8] = a1;
        *(bf16x8*)&Bs[r0 * 72 + kc0 * 8] = b0;
        *(bf16x8*)&Bs[r1 * 72 + kc0 * 8] = b1;
        __syncthreads();
        #pragma unroll
        for (int k32 = 0; k32 < 2; k32++) {
            bf16x8 bf = *(const bf16x8*)&Bs[(wvi*16 + col) * 72 + k32*32 + quad*8];
            #pragma unroll
            for (int ms = 0; ms < 4; ms++) {
                bf16x8 af = *(const bf16x8*)&As[(ms*16 + col) * 72 + k32*32 + quad*8];
                acc[ms] = __builtin_amdgcn_mfma_f32_16x16x32_bf16(af, bf, acc[ms], 0, 0, 0);
            }
        }
    }

    const float bn = bias[n0 + wvi*16 + col];
    const int h = blockIdx.y;
    #pragma unroll
    for (int ms = 0; ms < 4; ms++) {
        #pragma unroll
        for (int r = 0; r < 4; r++) {
            int m = m0 + ms*16 + quad*4 + r;
            int bb = m >> 9, l = m & 511;
            outp[(((size_t)(bb*NH + h)) * TSEQ + l) * HD + wvi*16 + col] =
                f2bf(acc[ms][r] + bn);
        }
    }
}

// ---------------------------------------------------------------------------
// Kernel 2: Kp[b][h][o][t][d] = (1/scale) * sum_i w1[(h*8+o)*12+i] * K[b][i][t][d]
// ---------------------------------------------------------------------------
__global__ __launch_bounds__(256) void kmix_kernel(
    const short* __restrict__ K,   // [B,12,T,64] bf16
    const float* __restrict__ w1,  // [96,12] fp32
    short* __restrict__ Kp)        // [B,12,8,T,64] bf16
{
    const int g  = blockIdx.x * 256 + threadIdx.x;   // chunk of 8 bf16
    const int d8 = g & 7;
    const int t  = (g >> 3) & 511;
    const int o  = (g >> 12) & 7;
    const int bh = g >> 15;          // b*12 + h
    const int h  = bh % NH;
    const int b  = bh / NH;

    float acc[8] = {};
    #pragma unroll
    for (int i = 0; i < 12; i++) {
        float w = w1[(h*8 + o)*12 + i] * RSCALE;
        bf16x8 kv = *(const bf16x8*)&K[(((size_t)(b*NH + i) * TSEQ) + t) * HD + d8*8];
        #pragma unroll
        for (int j = 0; j < 8; j++)
            acc[j] = fmaf(w, bf2f(kv[j]), acc[j]);
    }
    bf16x8 outv;
    #pragma unroll
    for (int j = 0; j < 8; j++) outv[j] = f2bf(acc[j]);
    *(bf16x8*)&Kp[(size_t)g * 8] = outv;
}

// ---------------------------------------------------------------------------
// Per-position talking-heads MLP (conv1 weights folded into Kp; b1 here).
// ---------------------------------------------------------------------------
DEVINL float mlp_eval(const float s[8],
                      const float b1r[8], const float w2r[8], float b2r,
                      const float w3r[4], const float b3r[4],
                      const float w4r[4], float b4r)
{
    float z2 = b2r;
    #pragma unroll
    for (int o = 0; o < 8; o++) {
        float z1 = fmaxf(s[o] + b1r[o], 0.0f);
        z2 = fmaf(z1, w2r[o], z2);
    }
    float r = b4r;
    #pragma unroll
    for (int j = 0; j < 4; j++) {
        float z3 = fmaxf(fmaf(z2, w3r[j], b3r[j]), 0.0f);
        r = fmaf(z3, w4r[j], r);
    }
    return r;
}

// group-of-8 padded row offset (conflict-free transpose writes + aligned b128 reads)
DEVINL int vrow(int r) { return r*40 + (r >> 3)*8; }

// ---------------------------------------------------------------------------
// Kernel 3: MFMA attention. Logical block = (b, h, l-tile 64, t-quarter 128).
// XCD swizzle: all 32 blocks of one (b,h) land on one XCD so the 512 KB Kp
// slice is fetched into that XCD's L2 once (HW assumption: consecutive
// blockIdx round-robin across 8 XCDs; speed-only heuristic).
// ---------------------------------------------------------------------------
__global__ __launch_bounds__(256, 3) void attn_mfma(
    const short* __restrict__ Qg,   // [B,12,T,64] bf16
    const short* __restrict__ Kg,   // [B,12,8,T,64] bf16
    const short* __restrict__ Vg,   // [B,12,T,64] bf16
    const float* __restrict__ b1, const float* __restrict__ w2,
    const float* __restrict__ b2, const float* __restrict__ w3,
    const float* __restrict__ b3, const float* __restrict__ w4,
    const float* __restrict__ b4,
    float* __restrict__ Pout)       // [768][64][64] fp32 partials
{
    __shared__ short Ks[256 * 72];   // [o*32+t][72]  (64d used)
    __shared__ short Vt[2624];       // transposed V: [d][t], group-padded
    __shared__ short As[2624];       // A weights:    [l][t], group-padded

    // --- XCD-aware swizzle: hw block -> (bh, lt, qtr)
    const int hw   = blockIdx.x;         // 0..767
    const int xcd  = hw & 7;
    const int slot = hw >> 3;            // 0..95
    const int bh   = xcd * 3 + (slot >> 5);   // 3 bh groups per XCD, 24 total
    const int inner= slot & 31;
    const int lt   = inner >> 2;
    const int qtr  = inner & 3;
    const int blk  = (bh * 8 + lt) * 4 + qtr;  // logical index for Pout

    const int h   = bh % NH;
    const int l0  = lt * 64;
    const int tb  = qtr * 128;

    const int tid  = threadIdx.x;
    const int wv   = tid >> 6;
    const int lane = tid & 63;
    const int col  = lane & 15;
    const int quad = lane >> 4;
    const int wl   = wv >> 1;   // l-half for S'
    const int wt   = wv & 1;    // t-half for S'

    float b1r[8], w2r[8], w3r[4], b3r[4], w4r[4];
    #pragma unroll
    for (int o = 0; o < 8; o++) { b1r[o] = b1[h*8+o]; w2r[o] = w2[h*8+o]; }
    #pragma unroll
    for (int j = 0; j < 4; j++) { w3r[j] = w3[h*4+j]; b3r[j] = b3[h*4+j]; w4r[j] = w4[h*4+j]; }
    const float b2r = b2[h];
    const float b4r = b4[h];

    bf16x8 qa[2][2];
    {
        const short* qb = Qg + ((size_t)bh * TSEQ + l0 + wl*32 + col) * HD;
        qa[0][0] = *(const bf16x8*)&qb[quad*8];
        qa[0][1] = *(const bf16x8*)&qb[32 + quad*8];
        qa[1][0] = *(const bf16x8*)&qb[16*HD + quad*8];
        qa[1][1] = *(const bf16x8*)&qb[16*HD + 32 + quad*8];
    }

    floatx4 accO[4];
    #pragma unroll
    for (int d16 = 0; d16 < 4; d16++) accO[d16] = (floatx4){0.f, 0.f, 0.f, 0.f};

    const short* kbase = Kg + (size_t)bh * 8 * TSEQ * HD;
    const short* vbase = Vg + (size_t)bh * TSEQ * HD;

    const int tl = tid >> 3;   // 0..31 staging row
    const int dc = tid & 7;    // staging 16B chunk

    for (int it = 0; it < 4; it++) {
        const int t0 = tb + it * 32;

        bf16x8 ktmp[8];
        #pragma unroll
        for (int o = 0; o < 8; o++)
            ktmp[o] = *(const bf16x8*)&kbase[((size_t)o * TSEQ + t0 + tl) * HD + dc*8];
        bf16x8 vtmp = *(const bf16x8*)&vbase[(size_t)(t0 + tl) * HD + dc*8];

        __syncthreads();

        #pragma unroll
        for (int o = 0; o < 8; o++)
            *(bf16x8*)&Ks[(o*32 + tl)*72 + dc*8] = ktmp[o];
        #pragma unroll
        for (int j = 0; j < 8; j++)
            Vt[vrow(dc*8 + j) + tl] = vtmp[j];   // transpose: Vt[d][t]

        __syncthreads();

        floatx4 accS[8][2];
        #pragma unroll
        for (int o = 0; o < 8; o++) {
            accS[o][0] = (floatx4){0.f, 0.f, 0.f, 0.f};
            accS[o][1] = (floatx4){0.f, 0.f, 0.f, 0.f};
        }
        #pragma unroll
        for (int k32 = 0; k32 < 2; k32++) {
            #pragma unroll
            for (int o = 0; o < 8; o++) {
                bf16x8 bf = *(const bf16x8*)&Ks[(o*32 + wt*16 + col)*72 + k32*32 + quad*8];
                accS[o][0] = __builtin_amdgcn_mfma_f32_16x16x32_bf16(qa[0][k32], bf, accS[o][0], 0, 0, 0);
                accS[o][1] = __builtin_amdgcn_mfma_f32_16x16x32_bf16(qa[1][k32], bf, accS[o][1], 0, 0, 0);
            }
        }

        #pragma unroll
        for (int li = 0; li < 2; li++) {
            #pragma unroll
            for (int r = 0; r < 4; r++) {
                float s[8];
                #pragma unroll
                for (int o = 0; o < 8; o++) s[o] = accS[o][li][r];
                float a = mlp_eval(s, b1r, w2r, b2r, w3r, b3r, w4r, b4r);
                As[vrow(wl*32 + li*16 + quad*4 + r) + wt*16 + col] = f2bf(a);
            }
        }
        __syncthreads();

        bf16x8 af = *(const bf16x8*)&As[vrow(wv*16 + col) + quad*8];
        #pragma unroll
        for (int d16 = 0; d16 < 4; d16++) {
            bf16x8 vf = *(const bf16x8*)&Vt[vrow(d16*16 + col) + quad*8];
            accO[d16] = __builtin_amdgcn_mfma_f32_16x16x32_bf16(af, vf, accO[d16], 0, 0, 0);
        }
    }

    float* pb = Pout + (size_t)blk * 64 * 64;
    #pragma unroll
    for (int d16 = 0; d16 < 4; d16++)
        #pragma unroll
        for (int r = 0; r < 4; r++)
            pb[(wv*16 + quad*4 + r) * 64 + d16*16 + col] = accO[d16][r];
}

// ---------------------------------------------------------------------------
// Kernel 4: sum 4 t-quarter partials, scatter to out[b][l][h*64+d].
// ---------------------------------------------------------------------------
__global__ __launch_bounds__(256) void reduce_kernel(
    const float* __restrict__ P, float* __restrict__ out)
{
    const int gi  = blockIdx.x * 256 + threadIdx.x;  // float4 units, 196608 total
    const int d4  = gi & 15;
    const int r   = (gi >> 4) & 63;
    const int grp = gi >> 10;            // (b*12+h)*8 + lt
    const int lt  = grp & 7;
    const int bh  = grp >> 3;
    const int h   = bh % NH;
    const int b   = bh / NH;

    const float* p0 = P + (size_t)grp * 4 * 4096 + r * 64 + d4 * 4;
    float4 s0 = *(const float4*)&p0[0];
    float4 s1 = *(const float4*)&p0[4096];
    float4 s2 = *(const float4*)&p0[8192];
    float4 s3 = *(const float4*)&p0[12288];
    float4 s;
    s.x = (s0.x + s1.x) + (s2.x + s3.x);
    s.y = (s0.y + s1.y) + (s2.y + s3.y);
    s.z = (s0.z + s1.z) + (s2.z + s3.z);
    s.w = (s0.w + s1.w) + (s2.w + s3.w);
    *(float4*)&out[((size_t)(b*TSEQ + lt*64 + r)) * E + h*64 + d4*4] = s;
}

// ---------------------------------------------------------------------------
extern "C" void kernel_launch(void* const* d_in, const int* in_sizes, int n_in,
                              void* d_out, int out_size, void* d_ws, size_t ws_size,
                              hipStream_t stream) {
    const float* x  = (const float*)d_in[0];
    const float* wq = (const float*)d_in[1];
    const float* bq = (const float*)d_in[2];
    const float* wk = (const float*)d_in[3];
    const float* bk = (const float*)d_in[4];
    const float* wv = (const float*)d_in[5];
    const float* bv = (const float*)d_in[6];
    const float* w1 = (const float*)d_in[7];
    const float* b1 = (const float*)d_in[8];
    const float* w2 = (const float*)d_in[9];
    const float* b2 = (const float*)d_in[10];
    const float* w3 = (const float*)d_in[11];
    const float* b3 = (const float*)d_in[12];
    const float* w4 = (const float*)d_in[13];
    const float* b4 = (const float*)d_in[14];
    float* out = (float*)d_out;

    short* Qb = (short*)d_ws;                       // 786432 bf16
    short* Kb = Qb + 786432;                        // 786432 bf16
    short* Vb = Kb + 786432;                        // 786432 bf16
    short* Kp = Vb + 786432;                        // 6291456 bf16
    float* P  = (float*)(Kp + 6291456);             // 3145728 fp32
    // bf16 conversions of x/wq/wk/wv alias the P region (P is written later)
    short* xb  = (short*)P;                         // 786432 bf16
    short* wqb = xb + 786432;                       // 589824 bf16
    short* wkb = wqb + 589824;
    short* wvb = wkb + 589824;

    convert_kernel<<<1248, 256, 0, stream>>>(x, wq, wk, wv, xb, wqb, wkb, wvb);
    qkv_mfma<<<dim3(16, 12, 3), 256, 0, stream>>>(xb, wqb, bq, wkb, bk, wvb, bv, Qb, Kb, Vb);
    kmix_kernel<<<3072, 256, 0, stream>>>(Kb, w1, Kp);
    attn_mfma<<<768, 256, 0, stream>>>(Qb, Kp, Vb, b1, w2, b2, w3, b3, w4, b4, P);
    reduce_kernel<<<768, 256, 0, stream>>>(P, out);
}